// Round 6
// baseline (183.311 us; speedup 1.0000x reference)
//
#include <hip/hip_runtime.h>
#include <hip/hip_bf16.h>

// Problem: out[b,l,:] = code[b,l,:] @ W[l]   (B=256, L=64, C=256, HW=1024, fp32)
#define B_  256
#define L_  64
#define C_  256
#define HW_ 1024

typedef float  floatx4 __attribute__((ext_vector_type(4)));
typedef __bf16 bf16x8  __attribute__((ext_vector_type(8)));
typedef __bf16 bf16x4  __attribute__((ext_vector_type(4)));

#define LDT_A 72    // A row stride in bf16 (144 B): A write/read banks uniform (verified)
#define LDB_ROW 128 // B row stride in BYTES (64 bf16; banks via XOR swizzle)

// Barrier that does NOT drain outstanding global loads (vmcnt).
#define BARRIER_LDS() asm volatile("s_waitcnt lgkmcnt(0)\n\ts_barrier" ::: "memory")

// B LDS XOR swizzle: element (n,k) at byte n*128 + ((c16 ^ g(n))*16) + (2k mod 16),
// c16 = k/8, g(n) = (n ^ (n>>2)) & 7.
__device__ __forceinline__ int bswz(int n) { return (n ^ (n >> 2)) & 7; }

// One block: 128m x 256n tile of group l. 512 threads = 8 waves (2x4),
// each wave 64x64 via 4x4 grid of mfma_f32_16x16x32_bf16 (m93-proven shape).
// Grid 512 (2 blocks/CU). Halves code re-read demand vs 128x128 tiling.
// Staging: both operands depth-1, issue-interleaved (stageA, prefA, stageB,
// prefB) so waits are vmcnt(8)/vmcnt(4) with one-iteration distance.
// B staging k-staggered per lane-octet: uniform LDS write banks, 128B-granular
// (full-L2-line) global segments.
__global__ __launch_bounds__(512, 4)
void gld_mfma_kernel(const float* __restrict__ code,
                     const float* __restrict__ W,
                     float* __restrict__ out)
{
    const int tid = threadIdx.x;

    // XCD swizzle: id = ll + 8*(m + 2*n4 + 8*lh); all 8 blocks of filter l
    // share id%8 -> same XCD -> W_l/code_l L2 locality.
    const int id  = blockIdx.x;
    const int ll  = id & 7;
    const int inr = id >> 3;
    const int m0  = (inr & 1) * 128;         // batch rows
    const int n0  = ((inr >> 1) & 3) * 256;  // HW cols
    const int l   = (inr >> 3) * 8 + ll;     // filter

    __shared__ __bf16 Alds[128 * LDT_A];           // A tile [m][k] bf16 (18.4 KB)
    __shared__ unsigned char Blds[256 * LDB_ROW];  // B tile [n][k] bf16 swizzled (32 KB)

    const int lane = tid & 63;
    const int wave = tid >> 6;          // 0..7
    const int wm = (wave >> 2) * 64;    // 0,64
    const int wn = (wave & 3) * 64;     // 0,64,128,192

    floatx4 acc[4][4];
    #pragma unroll
    for (int i = 0; i < 4; ++i)
        #pragma unroll
        for (int j = 0; j < 4; ++j)
            acc[i][j] = (floatx4)0.0f;

    // A staging: 128 rows x 64 k fp32 -> 4 float4/thread (fully coalesced)
    const int a_row = tid >> 4;          // 0..31 (4 passes of 32 rows)
    const int a_kc  = (tid & 15) * 4;
    // B staging: 64 k x 256 n fp32 -> 8 float4/thread (2 k-groups x 4 k-rows).
    // Lane-octet k-stagger: c8 = wave ^ (lane>>3) -> 128B global segments
    // (full L2 lines) + exactly-uniform LDS write banks.
    const int b_i  = lane;                       // n-quad 0..63 (n = 4*b_i+j)
    const int b_c8 = (wave ^ (lane >> 3)) & 7;   // 8B k-chunk; groups c8, c8+8

    const float* aBase = code + (size_t)m0 * (L_ * C_) + (size_t)l * C_ + a_kc;
    const float* wBase = W + (size_t)l * (C_ * HW_) + n0 + 4 * b_i;

    floatx4 Areg[4];      // depth-1
    floatx4 Breg[2][4];   // depth-1 (two k-groups)

    // B LDS write addresses for k-group 0 (t=1 is ^0x40: c8+8 flips bit2 of c16)
    int bwaddr[4];
    #pragma unroll
    for (int j = 0; j < 4; ++j) {
        const int row = 4 * b_i + j;
        bwaddr[j] = row * LDB_ROW + (((b_c8 >> 1) ^ bswz(row)) << 4) + ((b_c8 & 1) << 3);
    }

    // ---- prologue: A(0) then B(0) ----
    #pragma unroll
    for (int p = 0; p < 4; ++p)
        Areg[p] = *(const floatx4*)(aBase + (size_t)(p * 32 + a_row) * (L_ * C_));
    #pragma unroll
    for (int t = 0; t < 2; ++t)
        #pragma unroll
        for (int r = 0; r < 4; ++r)
            Breg[t][r] = *(const floatx4*)(wBase + (size_t)(4 * (b_c8 + 8 * t) + r) * HW_);

    #pragma unroll
    for (int kb = 0; kb < C_; kb += 64) {
        // ---- stage A (A(i) is 1 iter old; B(i)'s 8 loads outstanding -> vmcnt(8)) ----
        #pragma unroll
        for (int p = 0; p < 4; ++p) {
            bf16x4 h;
            h.x = (__bf16)Areg[p].x; h.y = (__bf16)Areg[p].y;
            h.z = (__bf16)Areg[p].z; h.w = (__bf16)Areg[p].w;
            *(bf16x4*)&Alds[(p * 32 + a_row) * LDT_A + a_kc] = h;
        }
        // ---- prefetch A(i+1) (so staging B below waits vmcnt(4), not 0) ----
        if (kb + 64 < C_) {
            #pragma unroll
            for (int p = 0; p < 4; ++p)
                Areg[p] = *(const floatx4*)(aBase + (size_t)(p * 32 + a_row) * (L_ * C_) + (kb + 64));
        }
        // ---- stage B ----
        #pragma unroll
        for (int t = 0; t < 2; ++t)
            #pragma unroll
            for (int j = 0; j < 4; ++j) {
                bf16x4 h;
                h.x = (__bf16)Breg[t][0][j]; h.y = (__bf16)Breg[t][1][j];
                h.z = (__bf16)Breg[t][2][j]; h.w = (__bf16)Breg[t][3][j];
                *(bf16x4*)&Blds[bwaddr[j] ^ (t << 6)] = h;
            }
        // ---- prefetch B(i+1) ----
        if (kb + 64 < C_) {
            #pragma unroll
            for (int t = 0; t < 2; ++t)
                #pragma unroll
                for (int r = 0; r < 4; ++r)
                    Breg[t][r] = *(const floatx4*)(wBase + (size_t)(kb + 64 + 4 * (b_c8 + 8 * t) + r) * HW_);
        }

        BARRIER_LDS();   // LDS writes visible; vmcnt NOT drained

        // ---- compute: 2 k-steps of 32, 16 MFMAs each ----
        #pragma unroll
        for (int ks = 0; ks < 2; ++ks) {
            bf16x8 af[4], bfr[4];
            const int koff = ks * 32 + (lane >> 4) * 8;
            const int c16  = koff >> 3;   // 4*ks + (lane>>4)
            #pragma unroll
            for (int i = 0; i < 4; ++i)
                af[i] = *(const bf16x8*)&Alds[(wm + i * 16 + (lane & 15)) * LDT_A + koff];
            #pragma unroll
            for (int j = 0; j < 4; ++j) {
                const int n = wn + j * 16 + (lane & 15);
                bfr[j] = *(const bf16x8*)&Blds[n * LDB_ROW + ((c16 ^ bswz(n)) << 4)];
            }
            #pragma unroll
            for (int i = 0; i < 4; ++i)
                #pragma unroll
                for (int j = 0; j < 4; ++j)
                    acc[i][j] = __builtin_amdgcn_mfma_f32_16x16x32_bf16(af[i], bfr[j], acc[i][j], 0, 0, 0);
        }

        BARRIER_LDS();   // all waves done reading before next overwrite
    }

    // ---- epilogue: C/D layout col=lane&15, row=(lane>>4)*4+reg ----
    const int col0 = lane & 15;
    const int row0 = (lane >> 4) * 4;
    #pragma unroll
    for (int i = 0; i < 4; ++i) {
        #pragma unroll
        for (int j = 0; j < 4; ++j) {
            const int m = m0 + wm + i * 16 + row0;
            const int n = n0 + wn + j * 16 + col0;
            float* o = out + (size_t)m * (L_ * HW_) + (size_t)l * HW_ + n;
            #pragma unroll
            for (int r = 0; r < 4; ++r)
                o[(size_t)r * (L_ * HW_)] = acc[i][j][r];
        }
    }
}

extern "C" void kernel_launch(void* const* d_in, const int* in_sizes, int n_in,
                              void* d_out, int out_size, void* d_ws, size_t ws_size,
                              hipStream_t stream) {
    const float* code = (const float*)d_in[0];   // [256, 64, 256] fp32
    const float* W    = (const float*)d_in[1];   // [64, 256, 1024] fp32
    float* out        = (float*)d_out;           // [256, 64, 32, 32] fp32

    gld_mfma_kernel<<<dim3(512), 512, 0, stream>>>(code, W, out);
}

// Round 7
// 134.920 us; speedup vs baseline: 1.3587x; 1.3587x over previous
//
#include <hip/hip_runtime.h>
#include <hip/hip_bf16.h>

// Problem: out[b,l,:] = code[b,l,:] @ W[l]   (B=256, L=64, C=256, HW=1024, fp32)
#define B_  256
#define L_  64
#define C_  256
#define HW_ 1024

typedef float  floatx4 __attribute__((ext_vector_type(4)));
typedef __bf16 bf16x8  __attribute__((ext_vector_type(8)));
typedef __bf16 bf16x4  __attribute__((ext_vector_type(4)));

#define LDB_ROW 512  // bytes per LDS n-row: 256 k * 2 B (full K resident)

// Barrier that does NOT drain outstanding global loads (vmcnt).
#define BARRIER_LDS() asm volatile("s_waitcnt lgkmcnt(0)\n\ts_barrier" ::: "memory")

// XOR chunk swizzle for B LDS: element (n,k) at byte
//   n*512 + ((c16 ^ g(n))*16) + (2k mod 16),   c16 = k/8, g(n) = (n ^ (n>>2)) & 7.
// Row stride 512 B == 0 mod 128 dwords -> banks depend only on swizzled chunk;
// staging b64 writes land 2-way per bank-pair (free, m136); reads ~uniform.
__device__ __forceinline__ int bswz(int n) { return (n ^ (n >> 2)) & 7; }

__device__ __forceinline__ bf16x8 cvt8(floatx4 lo, floatx4 hi) {
    bf16x8 o;
    o[0] = (__bf16)lo.x; o[1] = (__bf16)lo.y; o[2] = (__bf16)lo.z; o[3] = (__bf16)lo.w;
    o[4] = (__bf16)hi.x; o[5] = (__bf16)hi.y; o[6] = (__bf16)hi.z; o[7] = (__bf16)hi.w;
    return o;
}

// One block = (filter l, 128-col n-strip). Stage W[l][0:256][n0:n0+128] into
// LDS (bf16, transposed, swizzled) ONCE -> single barrier -> each of 8 waves
// computes a private 32m x 128n strip over the full K with no further
// barriers: A fragments straight from global (16B/lane, L2/L3-hot code),
// depth-2 register prefetch, 8 unrolled k-steps of mfma_f32_16x16x32_bf16.
__global__ __launch_bounds__(512, 2)
void gld_mfma_kernel(const float* __restrict__ code,
                     const float* __restrict__ W,
                     float* __restrict__ out)
{
    const int tid = threadIdx.x;

    // XCD swizzle: blocks of the same filter l share id%8 (code_l L2 reuse).
    const int id = blockIdx.x;
    const int ll = id & 7;
    const int n4 = (id >> 3) & 7;
    const int lh = id >> 6;
    const int l  = lh * 8 + ll;
    const int n0 = n4 * 128;

    __shared__ unsigned char Blds[128 * LDB_ROW];   // 64 KB -> 2 blocks/CU

    const int lane = tid & 63;
    const int wave = tid >> 6;          // 0..7

    // ---------------- stage W-strip (fp32 -> bf16, transpose, swizzle) -----
    // Thread owns n-quad (tid&31) x 16-k group (tid>>5): 16 coalesced float4
    // loads (each wave instr = 2x512B runs), 4x4 register transposes.
    const int b_i = tid & 31;
    const int b_g = tid >> 5;
    const float* wBase = W + (size_t)l * (C_ * HW_) + (size_t)(16 * b_g) * HW_ + n0 + 4 * b_i;

    floatx4 wr[4][4];
    #pragma unroll
    for (int u = 0; u < 4; ++u)
        #pragma unroll
        for (int r = 0; r < 4; ++r)
            wr[u][r] = *(const floatx4*)(wBase + (size_t)(4 * u + r) * HW_);

    // ---- issue A prefetch (ks=0,1) BEFORE staging: in flight across barrier
    const int wm    = wave * 32;                 // wave's private m-strip
    const int mrow0 = wm + (lane & 15);          // A-operand row (i=0)
    const int koff  = (lane >> 4) * 8;           // A-operand k sub-offset
    const float* aPtr0 = code + ((size_t)mrow0 * L_ + l) * C_ + koff;
    const float* aPtr1 = aPtr0 + (size_t)16 * (L_ * C_);   // i=1 rows (+16 m)

    floatx4 Ar[2][2][2];   // [ping][i][16B half]
    #pragma unroll
    for (int d = 0; d < 2; ++d) {
        Ar[d][0][0] = *(const floatx4*)(aPtr0 + d * 32);
        Ar[d][0][1] = *(const floatx4*)(aPtr0 + d * 32 + 4);
        Ar[d][1][0] = *(const floatx4*)(aPtr1 + d * 32);
        Ar[d][1][1] = *(const floatx4*)(aPtr1 + d * 32 + 4);
    }

    // ---- LDS writes (wait on wr loads only; A loads stay outstanding) ----
    #pragma unroll
    for (int u = 0; u < 4; ++u) {
        const int c8 = 4 * b_g + u;              // 8B k-chunk (k = 4*c8)
        #pragma unroll
        for (int j = 0; j < 4; ++j) {
            const int row = 4 * b_i + j;
            bf16x4 h;
            h.x = (__bf16)wr[u][0][j]; h.y = (__bf16)wr[u][1][j];
            h.z = (__bf16)wr[u][2][j]; h.w = (__bf16)wr[u][3][j];
            const int addr = row * LDB_ROW + (((c8 >> 1) ^ bswz(row)) << 4) + ((c8 & 1) << 3);
            *(bf16x4*)&Blds[addr] = h;
        }
    }

    BARRIER_LDS();   // the ONLY barrier; A prefetch stays in flight

    // ---------------- wave-private K-sweep, no barriers --------------------
    floatx4 acc[2][8];
    #pragma unroll
    for (int i = 0; i < 2; ++i)
        #pragma unroll
        for (int j = 0; j < 8; ++j)
            acc[i][j] = (floatx4)0.0f;

    #pragma unroll
    for (int ks = 0; ks < 8; ++ks) {
        const int pb = ks & 1;
        bf16x8 af[2];
        af[0] = cvt8(Ar[pb][0][0], Ar[pb][0][1]);
        af[1] = cvt8(Ar[pb][1][0], Ar[pb][1][1]);

        // depth-2 A prefetch for ks+2
        if (ks + 2 < 8) {
            const int kg = (ks + 2) * 32;
            Ar[pb][0][0] = *(const floatx4*)(aPtr0 + kg);
            Ar[pb][0][1] = *(const floatx4*)(aPtr0 + kg + 4);
            Ar[pb][1][0] = *(const floatx4*)(aPtr1 + kg);
            Ar[pb][1][1] = *(const floatx4*)(aPtr1 + kg + 4);
        }

        bf16x8 bfr[8];
        const int c16 = ks * 4 + (lane >> 4);
        #pragma unroll
        for (int j = 0; j < 8; ++j) {
            const int n = 16 * j + (lane & 15);
            bfr[j] = *(const bf16x8*)&Blds[n * LDB_ROW + ((c16 ^ bswz(n)) << 4)];
        }

        #pragma unroll
        for (int i = 0; i < 2; ++i)
            #pragma unroll
            for (int j = 0; j < 8; ++j)
                acc[i][j] = __builtin_amdgcn_mfma_f32_16x16x32_bf16(af[i], bfr[j], acc[i][j], 0, 0, 0);
    }

    // ---------------- epilogue: C/D layout col=lane&15, row=(lane>>4)*4+r --
    const int col0 = lane & 15;
    const int row0 = (lane >> 4) * 4;
    #pragma unroll
    for (int i = 0; i < 2; ++i) {
        #pragma unroll
        for (int j = 0; j < 8; ++j) {
            const int m = wm + i * 16 + row0;
            const int n = n0 + j * 16 + col0;
            float* o = out + (size_t)m * (L_ * HW_) + (size_t)l * HW_ + n;
            #pragma unroll
            for (int r = 0; r < 4; ++r)
                o[(size_t)r * (L_ * HW_)] = acc[i][j][r];
        }
    }
}

extern "C" void kernel_launch(void* const* d_in, const int* in_sizes, int n_in,
                              void* d_out, int out_size, void* d_ws, size_t ws_size,
                              hipStream_t stream) {
    const float* code = (const float*)d_in[0];   // [256, 64, 256] fp32
    const float* W    = (const float*)d_in[1];   // [64, 256, 1024] fp32
    float* out        = (float*)d_out;           // [256, 64, 32, 32] fp32

    gld_mfma_kernel<<<dim3(512), 512, 0, stream>>>(code, W, out);
}